// Round 4
// baseline (139.892 us; speedup 1.0000x reference)
//
#include <hip/hip_runtime.h>
#include <hip/hip_bf16.h>

typedef float f4v __attribute__((ext_vector_type(4)));
typedef float f32x4 __attribute__((ext_vector_type(4)));
typedef __bf16 bf16x8 __attribute__((ext_vector_type(8)));

#define GLDS16(gsrc, ldst)                                                  \
  __builtin_amdgcn_global_load_lds(                                         \
      (const __attribute__((address_space(1))) unsigned int*)(gsrc),        \
      (__attribute__((address_space(3))) unsigned int*)(ldst), 16, 0, 0)

__device__ __forceinline__ unsigned pack2bf(float lo, float hi) {
  unsigned short ua = __builtin_bit_cast(unsigned short, (__bf16)lo);
  unsigned short ub = __builtin_bit_cast(unsigned short, (__bf16)hi);
  return (unsigned)ua | ((unsigned)ub << 16);
}

// ---------------- kernel 1: modulation MLP -> s [16][512] (f32, ws) -------
__global__ __launch_bounds__(256) void mlp_kernel(
    const float* __restrict__ t,
    const float* __restrict__ W1, const float* __restrict__ b1,
    const float* __restrict__ W2, const float* __restrict__ b2,
    const float* __restrict__ W3, const float* __restrict__ b3,
    float* __restrict__ s_out) {
  __shared__ float tt[256];
  __shared__ float hh[256];
  const int b = blockIdx.x;
  const int tid = threadIdx.x;
  tt[tid] = t[b * 256 + tid];
  __syncthreads();
  float acc = b1[tid];
  {
    const f4v* wrow = (const f4v*)(W1 + tid * 256);
    #pragma unroll 16
    for (int k = 0; k < 64; ++k) {
      f4v wv = wrow[k];
      acc += wv[0] * tt[4 * k] + wv[1] * tt[4 * k + 1] +
             wv[2] * tt[4 * k + 2] + wv[3] * tt[4 * k + 3];
    }
  }
  float h = acc / (1.0f + expf(-acc));
  __syncthreads();
  hh[tid] = h;
  __syncthreads();
  acc = b2[tid];
  {
    const f4v* wrow = (const f4v*)(W2 + tid * 256);
    #pragma unroll 16
    for (int k = 0; k < 64; ++k) {
      f4v wv = wrow[k];
      acc += wv[0] * hh[4 * k] + wv[1] * hh[4 * k + 1] +
             wv[2] * hh[4 * k + 2] + wv[3] * hh[4 * k + 3];
    }
  }
  h = acc / (1.0f + expf(-acc));
  __syncthreads();
  tt[tid] = h;
  __syncthreads();
  #pragma unroll
  for (int rep = 0; rep < 2; ++rep) {
    const int o = rep * 256 + tid;
    float a3 = b3[o];
    const f4v* wrow = (const f4v*)(W3 + o * 256);
    #pragma unroll 16
    for (int k = 0; k < 64; ++k) {
      f4v wv = wrow[k];
      a3 += wv[0] * tt[4 * k] + wv[1] * tt[4 * k + 1] +
            wv[2] * tt[4 * k + 2] + wv[3] * tt[4 * k + 3];
    }
    s_out[b * 512 + o] = a3 + 1.0f;
  }
}

// ---------------- kernel 2: demod + bw (bf16) [16][512][512] --------------
__global__ __launch_bounds__(256) void modw_kernel(
    const float* __restrict__ weight, const float* __restrict__ s_in,
    unsigned short* __restrict__ bwq) {
  const int tid = threadIdx.x;
  const int wid = (blockIdx.x << 2) | (tid >> 6);
  const int b = wid >> 9;
  const int o = wid & 511;
  const int lane = tid & 63;
  const f4v* wp = (const f4v*)(weight + o * 512 + lane * 8);
  const f4v* sp = (const f4v*)(s_in + b * 512 + lane * 8);
  f4v w0 = wp[0], w1 = wp[1];
  f4v s0 = sp[0], s1 = sp[1];
  float p[8];
  p[0] = w0[0] * s0[0]; p[1] = w0[1] * s0[1];
  p[2] = w0[2] * s0[2]; p[3] = w0[3] * s0[3];
  p[4] = w1[0] * s1[0]; p[5] = w1[1] * s1[1];
  p[6] = w1[2] * s1[2]; p[7] = w1[3] * s1[3];
  float ss = 0.0f;
  #pragma unroll
  for (int i = 0; i < 8; ++i) ss += p[i] * p[i];
  #pragma unroll
  for (int off = 32; off; off >>= 1) ss += __shfl_xor(ss, off);
  const float d = rsqrtf(ss + 1e-8f);
  uint4 outw;
  outw.x = pack2bf(p[0] * d, p[1] * d);
  outw.y = pack2bf(p[2] * d, p[3] * d);
  outw.z = pack2bf(p[4] * d, p[5] * d);
  outw.w = pack2bf(p[6] * d, p[7] * d);
  *(uint4*)(bwq + ((size_t)(b * 512 + o)) * 512 + lane * 8) = outw;
}

// ---------------- kernel 3: batched GEMM out[b] = bw[b] @ x[b] ------------
// 4-deep x prefetch (named reg sets a/b/c/d), 4-deep A staging into 5
// rotating LDS buffers (A issued before x each step -> PACKB's auto vmcnt
// wait on x[it] drains A[it] by FIFO), double-buffered B, 1 barrier/step.
// LDS layouts: granule (kq, idx) at byte kq*2048 + (idx ^ ((idx>>3)&7))*16
// for both A (idx=m, source-swizzled GLDS) and B (idx=n, swizzled writes):
// b128 fragment reads and PACKB b64 writes both hit the bank minimum.
__global__ __launch_bounds__(256) void gemm_kernel(
    const float* __restrict__ x, const unsigned short* __restrict__ bwq,
    float* __restrict__ out) {
  __shared__ __align__(16) unsigned short AsBuf[5][4096];  // 40 KB
  __shared__ __align__(16) unsigned short BsBuf[2][4096];  // 16 KB

  const int bid = blockIdx.x;
  const int swz = ((bid & 7) << 8) | (bid >> 3);
  const int mt = swz & 3;
  const int nt = (swz >> 2) & 31;
  const int bb = swz >> 7;

  const int tid = threadIdx.x;
  const int lane = tid & 63;
  const int wv = tid >> 6;
  const int wr = wv >> 1, wc = wv & 1;

  const unsigned short* abase = bwq + ((size_t)(bb * 512 + mt * 128)) * 512;
  const float* xbase = x + ((size_t)bb * 512) * 4096 + nt * 128;

  // ---- x staging addressing (thread covers 4 k-rows x 4 n-cols) ---------
  const int pq = tid >> 5;  // 0..7
  const int lc = tid & 31;  // 0..31
  const float* xp = xbase + (size_t)(pq * 4) * 4096 + lc * 4;

  // ---- A staging: slots s0=tid, s1=256+tid; source pre-swizzled ---------
  const int s0 = tid, s1 = 256 + tid;
  const int kq0 = s0 >> 7, mp0 = s0 & 127;
  const int kq1 = s1 >> 7, mp1 = s1 & 127;
  const int m0 = mp0 ^ ((mp0 >> 3) & 7);
  const int m1 = mp1 ^ ((mp1 >> 3) & 7);
  const unsigned short* asrc0 = abase + m0 * 512 + kq0 * 8;
  const unsigned short* asrc1 = abase + m1 * 512 + kq1 * 8;
  const int aoff0 = s0 * 8;  // LDS ushort offset (linear: slot*16B)
  const int aoff1 = s1 * 8;

  // ---- PACKB write offsets (loop-invariant, swizzled) -------------------
  int bw_off[4];
  #pragma unroll
  for (int j = 0; j < 4; ++j) {
    const int n = lc * 4 + j;
    bw_off[j] = (pq >> 1) * 2048 + (n ^ ((n >> 3) & 7)) * 16 + (pq & 1) * 8;
  }

  // ---- fragment read offsets (swizzled) ---------------------------------
  const int kqL = lane >> 4;
  const int rL = lane & 15;
  int aro[4], bro[4];
  #pragma unroll
  for (int i = 0; i < 4; ++i) {
    const int m = wr * 64 + i * 16 + rL;
    aro[i] = kqL * 2048 + (m ^ ((m >> 3) & 7)) * 16;
    const int n = wc * 64 + i * 16 + rL;
    bro[i] = kqL * 2048 + (n ^ ((n >> 3) & 7)) * 16;
  }

  f32x4 acc[4][4] = {};
  f4v xa0, xa1, xa2, xa3, xb0, xb1, xb2, xb3;
  f4v xc0, xc1, xc2, xc3, xd0, xd1, xd2, xd3;

  unsigned short* pA0 = &AsBuf[0][0];
  unsigned short* pA1 = &AsBuf[1][0];
  unsigned short* pA2 = &AsBuf[2][0];
  unsigned short* pA3 = &AsBuf[3][0];
  unsigned short* pA4 = &AsBuf[4][0];
  char* bs0 = (char*)&BsBuf[0][0];
  char* bs1 = (char*)&BsBuf[1][0];

#define LOADXP(R0, R1, R2, R3, P)                                           \
  do {                                                                      \
    R0 = *(const f4v*)(P);                                                  \
    R1 = *(const f4v*)((P) + 4096);                                         \
    R2 = *(const f4v*)((P) + 8192);                                         \
    R3 = *(const f4v*)((P) + 12288);                                        \
  } while (0)

#define STAGEA(KOFF, PDST)                                                  \
  do {                                                                      \
    GLDS16(asrc0 + (KOFF), (PDST) + aoff0);                                 \
    GLDS16(asrc1 + (KOFF), (PDST) + aoff1);                                 \
  } while (0)

#define PACKB(R0, R1, R2, R3, BSP)                                          \
  do {                                                                      \
    _Pragma("unroll")                                                       \
    for (int j = 0; j < 4; ++j) {                                           \
      uint2 val;                                                            \
      val.x = pack2bf(R0[j], R1[j]);                                        \
      val.y = pack2bf(R2[j], R3[j]);                                        \
      *(uint2*)((BSP) + bw_off[j]) = val;                                   \
    }                                                                       \
  } while (0)

#define FENCE() asm volatile("" ::: "memory")
#define BAR()                                                               \
  do {                                                                      \
    asm volatile("s_waitcnt lgkmcnt(0)" ::: "memory");                      \
    __builtin_amdgcn_s_barrier();                                           \
    __builtin_amdgcn_sched_barrier(0);                                      \
  } while (0)

#define COMPUTE(PA, BSP)                                                    \
  do {                                                                      \
    const char* ab = (const char*)(PA);                                     \
    bf16x8 a0 = *(const bf16x8*)(ab + aro[0]);                              \
    bf16x8 a1 = *(const bf16x8*)(ab + aro[1]);                              \
    bf16x8 a2 = *(const bf16x8*)(ab + aro[2]);                              \
    bf16x8 a3 = *(const bf16x8*)(ab + aro[3]);                              \
    bf16x8 bf0 = *(const bf16x8*)((BSP) + bro[0]);                          \
    bf16x8 bf1 = *(const bf16x8*)((BSP) + bro[1]);                          \
    bf16x8 bf2 = *(const bf16x8*)((BSP) + bro[2]);                          \
    bf16x8 bf3 = *(const bf16x8*)((BSP) + bro[3]);                          \
    acc[0][0] = __builtin_amdgcn_mfma_f32_16x16x32_bf16(a0, bf0, acc[0][0], 0, 0, 0); \
    acc[0][1] = __builtin_amdgcn_mfma_f32_16x16x32_bf16(a0, bf1, acc[0][1], 0, 0, 0); \
    acc[0][2] = __builtin_amdgcn_mfma_f32_16x16x32_bf16(a0, bf2, acc[0][2], 0, 0, 0); \
    acc[0][3] = __builtin_amdgcn_mfma_f32_16x16x32_bf16(a0, bf3, acc[0][3], 0, 0, 0); \
    acc[1][0] = __builtin_amdgcn_mfma_f32_16x16x32_bf16(a1, bf0, acc[1][0], 0, 0, 0); \
    acc[1][1] = __builtin_amdgcn_mfma_f32_16x16x32_bf16(a1, bf1, acc[1][1], 0, 0, 0); \
    acc[1][2] = __builtin_amdgcn_mfma_f32_16x16x32_bf16(a1, bf2, acc[1][2], 0, 0, 0); \
    acc[1][3] = __builtin_amdgcn_mfma_f32_16x16x32_bf16(a1, bf3, acc[1][3], 0, 0, 0); \
    acc[2][0] = __builtin_amdgcn_mfma_f32_16x16x32_bf16(a2, bf0, acc[2][0], 0, 0, 0); \
    acc[2][1] = __builtin_amdgcn_mfma_f32_16x16x32_bf16(a2, bf1, acc[2][1], 0, 0, 0); \
    acc[2][2] = __builtin_amdgcn_mfma_f32_16x16x32_bf16(a2, bf2, acc[2][2], 0, 0, 0); \
    acc[2][3] = __builtin_amdgcn_mfma_f32_16x16x32_bf16(a2, bf3, acc[2][3], 0, 0, 0); \
    acc[3][0] = __builtin_amdgcn_mfma_f32_16x16x32_bf16(a3, bf0, acc[3][0], 0, 0, 0); \
    acc[3][1] = __builtin_amdgcn_mfma_f32_16x16x32_bf16(a3, bf1, acc[3][1], 0, 0, 0); \
    acc[3][2] = __builtin_amdgcn_mfma_f32_16x16x32_bf16(a3, bf2, acc[3][2], 0, 0, 0); \
    acc[3][3] = __builtin_amdgcn_mfma_f32_16x16x32_bf16(a3, bf3, acc[3][3], 0, 0, 0); \
  } while (0)

#define ROT5()                                                              \
  do {                                                                      \
    unsigned short* _t = pA0;                                               \
    pA0 = pA1; pA1 = pA2; pA2 = pA3; pA3 = pA4; pA4 = _t;                   \
  } while (0)

  // ---- prologue: A[0..3] staged (A-first per step), x[0..3] in regs -----
  const long long XS = 32LL * 4096;  // floats per K-step
  STAGEA(0, pA0);   FENCE();  LOADXP(xa0, xa1, xa2, xa3, xp);
  STAGEA(32, pA1);  FENCE();  LOADXP(xb0, xb1, xb2, xb3, xp + XS);
  STAGEA(64, pA2);  FENCE();  LOADXP(xc0, xc1, xc2, xc3, xp + 2 * XS);
  STAGEA(96, pA3);  FENCE();  LOADXP(xd0, xd1, xd2, xd3, xp + 3 * XS);

  const float* xq = xp + 4 * XS;
  int koff = 128;  // ushort k-offset of the step being staged (step 4)

  // ---- main loop: 4 macro-iters x 4 steps -------------------------------
  for (int q = 0; q < 4; ++q) {
    // step 4q+0: set a, B0
    PACKB(xa0, xa1, xa2, xa3, bs0);
    if (q < 3) { STAGEA(koff, pA4); FENCE();
                 LOADXP(xa0, xa1, xa2, xa3, xq); xq += XS; koff += 32; }
    BAR(); COMPUTE(pA0, bs0); ROT5();
    // step 4q+1: set b, B1
    PACKB(xb0, xb1, xb2, xb3, bs1);
    if (q < 3) { STAGEA(koff, pA4); FENCE();
                 LOADXP(xb0, xb1, xb2, xb3, xq); xq += XS; koff += 32; }
    BAR(); COMPUTE(pA0, bs1); ROT5();
    // step 4q+2: set c, B0
    PACKB(xc0, xc1, xc2, xc3, bs0);
    if (q < 3) { STAGEA(koff, pA4); FENCE();
                 LOADXP(xc0, xc1, xc2, xc3, xq); xq += XS; koff += 32; }
    BAR(); COMPUTE(pA0, bs0); ROT5();
    // step 4q+3: set d, B1
    PACKB(xd0, xd1, xd2, xd3, bs1);
    if (q < 3) { STAGEA(koff, pA4); FENCE();
                 LOADXP(xd0, xd1, xd2, xd3, xq); xq += XS; koff += 32; }
    BAR(); COMPUTE(pA0, bs1); ROT5();
  }

  // ---- epilogue ---------------------------------------------------------
  const size_t ob =
      ((size_t)(bb * 512 + mt * 128 + wr * 64 + ((lane >> 4) << 2))) * 4096 +
      nt * 128 + wc * 64 + (lane & 15);
  #pragma unroll
  for (int mi = 0; mi < 4; ++mi)
    #pragma unroll
    for (int ni = 0; ni < 4; ++ni)
      #pragma unroll
      for (int jj = 0; jj < 4; ++jj)
        out[ob + (size_t)(mi * 16 + jj) * 4096 + ni * 16] = acc[mi][ni][jj];

#undef LOADXP
#undef STAGEA
#undef PACKB
#undef FENCE
#undef BAR
#undef COMPUTE
#undef ROT5
}

extern "C" void kernel_launch(void* const* d_in, const int* in_sizes, int n_in,
                              void* d_out, int out_size, void* d_ws, size_t ws_size,
                              hipStream_t stream) {
  const float* x      = (const float*)d_in[0];
  const float* t      = (const float*)d_in[1];
  const float* weight = (const float*)d_in[2];
  const float* W1     = (const float*)d_in[3];
  const float* b1     = (const float*)d_in[4];
  const float* W2     = (const float*)d_in[5];
  const float* b2     = (const float*)d_in[6];
  const float* W3     = (const float*)d_in[7];
  const float* b3     = (const float*)d_in[8];
  float* out = (float*)d_out;

  float* s_ws = (float*)d_ws;
  unsigned short* bwq = (unsigned short*)((char*)d_ws + 32 * 1024);

  mlp_kernel<<<16, 256, 0, stream>>>(t, W1, b1, W2, b2, W3, b3, s_ws);
  modw_kernel<<<2048, 256, 0, stream>>>(weight, s_ws, bwq);
  gemm_kernel<<<2048, 256, 0, stream>>>(x, bwq, out);
}